// Round 3
// baseline (240.421 us; speedup 1.0000x reference)
//
#include <hip/hip_runtime.h>

// DropGCN: out = relu( mean_r( diag(k_r) A diag(k_r) X ) @ W^T + b )
//  == Y[8192,160] = A @ Xm   (Xm[:, r*32+d] = k_r .* X[:,d], bf16)
//  then per-row masked mean over the 5 replica slices, @W^T, +b, relu.
//
// Round 3: gemm reads Xm fragments DIRECTLY from global (L2-resident 2.6 MB
// image) -- no LDS, no barriers (r2's 8-way-conflicted ds_read_b128 was the
// bottleneck). 2 m-tiles per wave amortize fragment traffic. KS=8 K-split.

#define N_NODES   8192
#define NSLICES   256          // 8192/32 K-slices
#define NCOLS     160          // 5 replicas * 32 dims
#define SLICE_US  5120         // ushorts per K-slice image (160*32)
#define MASK_N    40960        // 5*8192 mask elements
#define MASK_WS   65536        // ws bytes reserved for normalized mask

typedef __attribute__((ext_vector_type(4))) float f32x4;
typedef __attribute__((ext_vector_type(8))) short bf16x8;

__device__ __forceinline__ unsigned short f2bf(float f) {
  // round-to-nearest-even f32 -> bf16 bits (prep path)
  unsigned int u = __builtin_bit_cast(unsigned int, f);
  return (unsigned short)((u + 0x7FFFu + ((u >> 16) & 1u)) >> 16);
}

__device__ __forceinline__ unsigned pack_bf(float lo, float hi) {
  // two f32 -> packed bf16 pair (round-to-nearest, ties-up; bias < 2^-9 rel)
  unsigned u0 = __builtin_bit_cast(unsigned, lo) + 0x8000u;
  unsigned u1 = __builtin_bit_cast(unsigned, hi) + 0x8000u;
  return (u1 & 0xFFFF0000u) | (u0 >> 16);
}

// ---------------------------------------------------------------------------
// mask_norm: keep_mask may arrive as u8 bools or i32/f32 words; normalize u8.
// ---------------------------------------------------------------------------
__global__ __launch_bounds__(256) void mask_norm_kernel(
    const void* __restrict__ raw, unsigned char* __restrict__ mk) {
  __shared__ int mode32;
  if (threadIdx.x == 0) {
    const unsigned int* w = (const unsigned int*)raw;
    int ok = 1;
    for (int i = 0; i < 64; ++i) {
      unsigned int v = w[i];
      if (!(v <= 1u || v == 0x3F800000u)) { ok = 0; break; }
    }
    mode32 = ok;
  }
  __syncthreads();
  int idx = blockIdx.x * 256 + threadIdx.x;
  unsigned char r;
  if (mode32) r = (unsigned char)(((const unsigned int*)raw)[idx] != 0u);
  else        r = (unsigned char)(((const unsigned char*)raw)[idx] != 0);
  mk[idx] = r;
}

// ---------------------------------------------------------------------------
// prep: XmG[s][n][kk] = bf16( mk[r][j] ? X[j][d] : 0 ), j = s*32+kk, n=r*32+d
// ---------------------------------------------------------------------------
__global__ __launch_bounds__(256) void prep_kernel(
    const float* __restrict__ X, const unsigned char* __restrict__ mk,
    unsigned short* __restrict__ XmG) {
  int tid = blockIdx.x * 256 + threadIdx.x;   // 0 .. 160*8192-1
  int j = tid & (N_NODES - 1);
  int n = tid >> 13;
  int r = n >> 5, d = n & 31;
  float v = mk[r * N_NODES + j] ? X[j * 32 + d] : 0.0f;
  int s = j >> 5, kk = j & 31;
  XmG[s * SLICE_US + n * 32 + kk] = f2bf(v);
}

// ---------------------------------------------------------------------------
// gemm: block = 4 waves x 32 rows = 128 rows, all 160 cols, K = 8192/KS.
// Wave: 2 m-tiles of 16. A-op = Xm^T fragment loaded straight from XmG
// (16 B contiguous per lane; a wave's fragment = 1 KB fully-coalesced block).
// B-op = A-matrix rows (2x16B per lane per tile from global, nontemporal,
// packed to bf16 in-register). No LDS, no barriers.
// D lane map (verified r2): acc[nt][jj] = Y[tile_m + n0][nt*16 + kg*4 + jj].
// Partials -> ws as C^T [KS][160][8192] f32.
// ---------------------------------------------------------------------------
__global__ __launch_bounds__(256, 2) void gemm_kernel(
    const float* __restrict__ A, const unsigned short* __restrict__ XmG,
    float* __restrict__ part, int KS) {
  const int tid  = threadIdx.x;
  const int lane = tid & 63;
  const int w    = tid >> 6;        // wave 0..3
  const int n0   = lane & 15;
  const int kg   = lane >> 4;       // k-group 0..3 (8 elems each)
  const int steps  = NSLICES / KS;
  const int s_base = blockIdx.y * steps;
  const int base_m = blockIdx.x * 128 + w * 32;

  // A rows for the wave's two 16-row tiles
  const float* aptr0 =
      A + (size_t)(base_m + n0) * N_NODES + s_base * 32 + kg * 8;
  const float* aptr1 = aptr0 + (size_t)16 * N_NODES;
  // Xm fragment source: 16 B contiguous per lane, identical layout to r2 LDS
  const unsigned short* xptr = XmG + (size_t)s_base * SLICE_US + n0 * 32 + kg * 8;

  f32x4 acc0[10], acc1[10];
#pragma unroll
  for (int i = 0; i < 10; ++i) {
    acc0[i] = (f32x4){0.f, 0.f, 0.f, 0.f};
    acc1[i] = (f32x4){0.f, 0.f, 0.f, 0.f};
  }

  // register prefetch of step-0 A chunks
  f32x4 a0  = __builtin_nontemporal_load((const f32x4*)aptr0);
  f32x4 a0b = __builtin_nontemporal_load((const f32x4*)(aptr0 + 4));
  f32x4 a1  = __builtin_nontemporal_load((const f32x4*)aptr1);
  f32x4 a1b = __builtin_nontemporal_load((const f32x4*)(aptr1 + 4));

  for (int step = 0; step < steps; ++step) {
    // prefetch next step's A registers (streaming, nontemporal)
    const int nxt = (step + 1 < steps) ? (step + 1) : step;
    f32x4 na0  = __builtin_nontemporal_load((const f32x4*)(aptr0 + (size_t)nxt * 32));
    f32x4 na0b = __builtin_nontemporal_load((const f32x4*)(aptr0 + (size_t)nxt * 32 + 4));
    f32x4 na1  = __builtin_nontemporal_load((const f32x4*)(aptr1 + (size_t)nxt * 32));
    f32x4 na1b = __builtin_nontemporal_load((const f32x4*)(aptr1 + (size_t)nxt * 32 + 4));

    // pack B fragments (k-map matches A-op fragment's; permutation cancels)
    union { bf16x8 v; unsigned u[4]; } b0, b1;
    b0.u[0] = pack_bf(a0[0], a0[1]);   b0.u[1] = pack_bf(a0[2], a0[3]);
    b0.u[2] = pack_bf(a0b[0], a0b[1]); b0.u[3] = pack_bf(a0b[2], a0b[3]);
    b1.u[0] = pack_bf(a1[0], a1[1]);   b1.u[1] = pack_bf(a1[2], a1[3]);
    b1.u[2] = pack_bf(a1b[0], a1b[1]); b1.u[3] = pack_bf(a1b[2], a1b[3]);

    const unsigned short* xs = xptr + (size_t)step * SLICE_US;
#pragma unroll
    for (int nt = 0; nt < 10; ++nt) {
      bf16x8 af = *(const bf16x8*)(xs + nt * 512);
      acc0[nt] = __builtin_amdgcn_mfma_f32_16x16x32_bf16(af, b0.v, acc0[nt], 0, 0, 0);
      acc1[nt] = __builtin_amdgcn_mfma_f32_16x16x32_bf16(af, b1.v, acc1[nt], 0, 0, 0);
    }
    a0 = na0; a0b = na0b; a1 = na1; a1b = na1b;
  }

  // store C^T partials part[s][n][m], coalesced in m (16-lane groups)
  float* p0 = part + (size_t)blockIdx.y * NCOLS * N_NODES + base_m + n0;
  float* p1 = p0 + 16;
#pragma unroll
  for (int nt = 0; nt < 10; ++nt) {
#pragma unroll
    for (int jj = 0; jj < 4; ++jj) {
      int n = nt * 16 + kg * 4 + jj;
      __builtin_nontemporal_store(acc0[nt][jj], p0 + (size_t)n * N_NODES);
      __builtin_nontemporal_store(acc1[nt][jj], p1 + (size_t)n * N_NODES);
    }
  }
}

// ---------------------------------------------------------------------------
// epi: z[m,d] = 0.2 * sum_{s, r: mk[r][m]} part[s][r*32+d][m];
//      out[m,o] = relu(b[o] + sum_d z[d] * W[o,d])
// ---------------------------------------------------------------------------
__global__ __launch_bounds__(64) void epi_kernel(
    const float* __restrict__ part, const unsigned char* __restrict__ mk,
    const float* __restrict__ W, const float* __restrict__ bias,
    float* __restrict__ out, int KS) {
  int m = blockIdx.x * 64 + threadIdx.x;
  float z[32];
#pragma unroll
  for (int d = 0; d < 32; ++d) z[d] = 0.f;
  for (int s = 0; s < KS; ++s) {
    for (int r = 0; r < 5; ++r) {
      if (mk[r * N_NODES + m]) {
        const float* p = part + ((size_t)s * NCOLS + r * 32) * N_NODES + m;
#pragma unroll
        for (int d = 0; d < 32; ++d) z[d] += p[(size_t)d * N_NODES];
      }
    }
  }
#pragma unroll
  for (int d = 0; d < 32; ++d) z[d] *= 0.2f;
#pragma unroll
  for (int o = 0; o < 32; ++o) {
    float a = bias[o];
#pragma unroll
    for (int d = 0; d < 32; ++d) a = fmaf(z[d], W[o * 32 + d], a);
    out[(size_t)m * 32 + o] = fmaxf(a, 0.f);
  }
}

extern "C" void kernel_launch(void* const* d_in, const int* in_sizes, int n_in,
                              void* d_out, int out_size, void* d_ws, size_t ws_size,
                              hipStream_t stream) {
  const float* A = (const float*)d_in[0];
  const float* X = (const float*)d_in[1];
  const float* W = (const float*)d_in[2];
  const float* b = (const float*)d_in[3];
  const void*  keep_raw = (const void*)d_in[4];
  float* out = (float*)d_out;

  const size_t xm_bytes   = (size_t)NSLICES * SLICE_US * 2;   // 2,621,440
  const size_t part_bytes = (size_t)NCOLS * N_NODES * 4;      // 5,242,880
  const size_t base = MASK_WS + xm_bytes;

  int KS = 1;
  if      (ws_size >= base + 8 * part_bytes) KS = 8;
  else if (ws_size >= base + 4 * part_bytes) KS = 4;
  else if (ws_size >= base + 2 * part_bytes) KS = 2;
  if (ws_size < base + part_bytes) return;   // ws too small: fail loudly

  unsigned char* mk = (unsigned char*)d_ws;
  unsigned short* XmG = (unsigned short*)((char*)d_ws + MASK_WS);
  float* part = (float*)((char*)d_ws + base);

  mask_norm_kernel<<<dim3(MASK_N / 256), 256, 0, stream>>>(keep_raw, mk);
  prep_kernel<<<dim3((N_NODES * NCOLS) / 256), 256, 0, stream>>>(X, mk, XmG);
  gemm_kernel<<<dim3(N_NODES / 128, KS), 256, 0, stream>>>(A, XmG, part, KS);
  epi_kernel<<<dim3(N_NODES / 64), 64, 0, stream>>>(part, mk, W, b, out, KS);
}

// Round 4
// 97.372 us; speedup vs baseline: 2.4691x; 2.4691x over previous
//
#include <hip/hip_runtime.h>

// DropGCN: out = relu( mean_r( diag(k_r) A diag(k_r) X ) @ W^T + b )
//  == Y[8192,160] = A @ Xm   (Xm[:, r*32+d] = k_r .* X[:,d], bf16)
//  then per-row masked mean over the 5 replica slices, @W^T, +b, relu.
//
// Round 4: traffic-minimized. 256-row blocks (8 waves x 2 m-tiles) cut Xm
// re-reads 4x; replica mask-mean fused into gemm epilogue (partials 8 MB,
// not 42 MB C^T); double-buffered LDS slice, 1 barrier/step, reg-staged with
// XOR-swizzled addresses (gemm-local; prep layout unchanged from passing r2).

#define N_NODES   8192
#define NSLICES   256          // 8192/32 K-slices
#define NCOLS     160          // 5 replicas * 32 dims
#define SLICE_US  5120         // ushorts per K-slice image (160*32)
#define MASK_N    40960        // 5*8192 mask elements
#define MASK_WS   65536        // ws bytes reserved for normalized mask
#define KSPLIT    8
#define STEPS     (NSLICES / KSPLIT)   // 32 K-steps per block

typedef __attribute__((ext_vector_type(4))) float f32x4;
typedef __attribute__((ext_vector_type(8))) short bf16x8;

__device__ __forceinline__ unsigned short f2bf(float f) {
  // round-to-nearest-even f32 -> bf16 bits (prep path)
  unsigned int u = __builtin_bit_cast(unsigned int, f);
  return (unsigned short)((u + 0x7FFFu + ((u >> 16) & 1u)) >> 16);
}

__device__ __forceinline__ unsigned pack_bf(float lo, float hi) {
  // two f32 -> packed bf16 pair (round-to-nearest ties-up; verified r3)
  unsigned u0 = __builtin_bit_cast(unsigned, lo) + 0x8000u;
  unsigned u1 = __builtin_bit_cast(unsigned, hi) + 0x8000u;
  return (u1 & 0xFFFF0000u) | (u0 >> 16);
}

// ---------------------------------------------------------------------------
// mask_norm: keep_mask may arrive as u8 bools or i32/f32 words; normalize u8.
// ---------------------------------------------------------------------------
__global__ __launch_bounds__(256) void mask_norm_kernel(
    const void* __restrict__ raw, unsigned char* __restrict__ mk) {
  __shared__ int mode32;
  if (threadIdx.x == 0) {
    const unsigned int* w = (const unsigned int*)raw;
    int ok = 1;
    for (int i = 0; i < 64; ++i) {
      unsigned int v = w[i];
      if (!(v <= 1u || v == 0x3F800000u)) { ok = 0; break; }
    }
    mode32 = ok;
  }
  __syncthreads();
  int idx = blockIdx.x * 256 + threadIdx.x;
  unsigned char r;
  if (mode32) r = (unsigned char)(((const unsigned int*)raw)[idx] != 0u);
  else        r = (unsigned char)(((const unsigned char*)raw)[idx] != 0);
  mk[idx] = r;
}

// ---------------------------------------------------------------------------
// prep: XmG[s][n][kk] = bf16( mk[r][j] ? X[j][d] : 0 ), j = s*32+kk, n=r*32+d
// (linear layout, unchanged from passing r2)
// ---------------------------------------------------------------------------
__global__ __launch_bounds__(256) void prep_kernel(
    const float* __restrict__ X, const unsigned char* __restrict__ mk,
    unsigned short* __restrict__ XmG) {
  int tid = blockIdx.x * 256 + threadIdx.x;   // 0 .. 160*8192-1
  int j = tid & (N_NODES - 1);
  int n = tid >> 13;
  int r = n >> 5, d = n & 31;
  float v = mk[r * N_NODES + j] ? X[j * 32 + d] : 0.0f;
  int s = j >> 5, kk = j & 31;
  XmG[s * SLICE_US + n * 32 + kk] = f2bf(v);
}

// ---------------------------------------------------------------------------
// gemm: block = 8 waves x 32 rows = 256 rows, all 160 cols, K-range 1024.
// LDS double-buffer of one 10 KB K-slice, 1 barrier/step, reg-staged with
// XOR swizzle: slice ushort (n*32 + kg*8 + e) lives at LDS ushort
//   n*32 + ((kg ^ ((n>>1)&3))*8) + e        [(n>>1)&3 == (n0>>1)&3 for reads]
// MFMA: A-op = Xm^T fragment (LDS), B-op = A-matrix rows (reg, bf16-packed).
// Verified D map (r2): acc[nt][jj] = Y[tile_m + n0][nt*16 + kg*4 + jj].
// Epilogue fuses replica mask-mean: even nt -> d = kg*4+jj (r = nt/2),
// odd nt -> d+16. partZ[sy][m][d] f32.
// ---------------------------------------------------------------------------
__global__ __launch_bounds__(512, 2) void gemm_kernel(
    const float* __restrict__ A, const unsigned short* __restrict__ XmG,
    const unsigned char* __restrict__ mk, float* __restrict__ partZ) {
  __shared__ __align__(16) unsigned short xm[2][SLICE_US];   // 20 KB

  const int tid  = threadIdx.x;
  const int lane = tid & 63;
  const int w    = tid >> 6;        // wave 0..7
  const int n0   = lane & 15;
  const int kg   = lane >> 4;       // k-group 0..3 (8 elems each)
  const int sy   = blockIdx.y;      // k-split 0..7
  const int s_base = sy * STEPS;
  const int base_m = blockIdx.x * 256 + w * 32;   // wave owns 32 rows

  // A rows for the wave's two 16-row tiles
  const float* aptr0 =
      A + (size_t)(base_m + n0) * N_NODES + s_base * 32 + kg * 8;
  const float* aptr1 = aptr0 + (size_t)16 * N_NODES;

  // staging: thread stages chunk c0=tid (and c1=tid+512 if tid<128);
  // chunk c = 16 B at slice ushort c*8 -> n = c>>2, kgs = c&3
  const unsigned short* xsrc = XmG + (size_t)s_base * SLICE_US;
  const int c0 = tid, n_c0 = c0 >> 2;
  const int off0 = n_c0 * 32 + (((c0 & 3) ^ ((n_c0 >> 1) & 3)) << 3);
  const int c1 = tid + 512, n_c1 = c1 >> 2;
  const int off1 = n_c1 * 32 + (((c1 & 3) ^ ((n_c1 >> 1) & 3)) << 3);
  const bool has2 = (tid < 128);    // 640 chunks over 512 threads

  // fragment read base (swizzled slot depends only on n0,kg)
  const unsigned short* frag0 =
      &xm[0][0] + n0 * 32 + ((kg ^ ((n0 >> 1) & 3)) << 3);

  f32x4 acc0[10], acc1[10];
#pragma unroll
  for (int i = 0; i < 10; ++i) {
    acc0[i] = (f32x4){0.f, 0.f, 0.f, 0.f};
    acc1[i] = (f32x4){0.f, 0.f, 0.f, 0.f};
  }

  // prologue: slice 0 -> regs -> LDS buf0; slice 1 -> regs; A step-0 regs
  bf16x8 sa = *(const bf16x8*)(xsrc + c0 * 8);
  bf16x8 sb2 = sa;
  if (has2) sb2 = *(const bf16x8*)(xsrc + c1 * 8);
  f32x4 a0  = __builtin_nontemporal_load((const f32x4*)aptr0);
  f32x4 a0b = __builtin_nontemporal_load((const f32x4*)(aptr0 + 4));
  f32x4 a1  = __builtin_nontemporal_load((const f32x4*)aptr1);
  f32x4 a1b = __builtin_nontemporal_load((const f32x4*)(aptr1 + 4));
  *(bf16x8*)(&xm[0][off0]) = sa;
  if (has2) *(bf16x8*)(&xm[0][off1]) = sb2;
  sa = *(const bf16x8*)(xsrc + SLICE_US + c0 * 8);
  if (has2) sb2 = *(const bf16x8*)(xsrc + SLICE_US + c1 * 8);
  __syncthreads();

  int cur = 0;
  for (int step = 0; step < STEPS; ++step) {
    // stage slice step+1 into the other buffer (its prior readers finished
    // before the barrier that ended step-1)
    if (step + 1 < STEPS) {
      unsigned short* dst = &xm[cur ^ 1][0];
      *(bf16x8*)(dst + off0) = sa;
      if (has2) *(bf16x8*)(dst + off1) = sb2;
    }
    // issue global load of slice step+2 (lands during compute + barrier)
    if (step + 2 < STEPS) {
      const unsigned short* s2 = xsrc + (size_t)(step + 2) * SLICE_US;
      sa = *(const bf16x8*)(s2 + c0 * 8);
      if (has2) sb2 = *(const bf16x8*)(s2 + c1 * 8);
    }
    // prefetch next step's A registers (streaming)
    const int nxt = (step + 1 < STEPS) ? (step + 1) : step;
    f32x4 na0  = __builtin_nontemporal_load((const f32x4*)(aptr0 + (size_t)nxt * 32));
    f32x4 na0b = __builtin_nontemporal_load((const f32x4*)(aptr0 + (size_t)nxt * 32 + 4));
    f32x4 na1  = __builtin_nontemporal_load((const f32x4*)(aptr1 + (size_t)nxt * 32));
    f32x4 na1b = __builtin_nontemporal_load((const f32x4*)(aptr1 + (size_t)nxt * 32 + 4));

    // pack B fragments (same lane->k map as A-op; permutation cancels)
    union { bf16x8 v; unsigned u[4]; } b0, b1;
    b0.u[0] = pack_bf(a0[0], a0[1]);   b0.u[1] = pack_bf(a0[2], a0[3]);
    b0.u[2] = pack_bf(a0b[0], a0b[1]); b0.u[3] = pack_bf(a0b[2], a0b[3]);
    b1.u[0] = pack_bf(a1[0], a1[1]);   b1.u[1] = pack_bf(a1[2], a1[3]);
    b1.u[2] = pack_bf(a1b[0], a1b[1]); b1.u[3] = pack_bf(a1b[2], a1b[3]);

    const unsigned short* fb = frag0 + cur * SLICE_US;
#pragma unroll
    for (int nt = 0; nt < 10; ++nt) {
      bf16x8 af = *(const bf16x8*)(fb + nt * 512);
      acc0[nt] = __builtin_amdgcn_mfma_f32_16x16x32_bf16(af, b0.v, acc0[nt], 0, 0, 0);
      acc1[nt] = __builtin_amdgcn_mfma_f32_16x16x32_bf16(af, b1.v, acc1[nt], 0, 0, 0);
    }
    __syncthreads();   // reads of buf[cur] done; buf[cur^1] writes visible
    cur ^= 1;
    a0 = na0; a0b = na0b; a1 = na1; a1b = na1b;
  }

  // fused replica mask-mean epilogue:
  // acc[2t][jj]  = Y[m][32t + kg*4+jj]      (d = kg*4+jj,   r = t)
  // acc[2t+1][jj]= Y[m][32t + 16 + kg*4+jj] (d = kg*4+jj+16, r = t)
  const int m0g = base_m + n0;
  const int m1g = m0g + 16;
  float w0[5], w1[5];
#pragma unroll
  for (int t = 0; t < 5; ++t) {
    w0[t] = mk[t * N_NODES + m0g] ? 0.2f : 0.0f;
    w1[t] = mk[t * N_NODES + m1g] ? 0.2f : 0.0f;
  }
  f32x4 zA0 = (f32x4){0.f,0.f,0.f,0.f}, zB0 = zA0, zA1 = zA0, zB1 = zA0;
#pragma unroll
  for (int t = 0; t < 5; ++t) {
    zA0 += w0[t] * acc0[2 * t];
    zB0 += w0[t] * acc0[2 * t + 1];
    zA1 += w1[t] * acc1[2 * t];
    zB1 += w1[t] * acc1[2 * t + 1];
  }
  float* p0 = partZ + ((size_t)sy * N_NODES + m0g) * 32 + kg * 4;
  *(f32x4*)(p0)      = zA0;
  *(f32x4*)(p0 + 16) = zB0;
  float* p1 = partZ + ((size_t)sy * N_NODES + m1g) * 32 + kg * 4;
  *(f32x4*)(p1)      = zA1;
  *(f32x4*)(p1 + 16) = zB1;
}

// ---------------------------------------------------------------------------
// epi: z[m][d] = sum_s partZ[s][m][d];  out[m][o] = relu(b[o] + z . W[o])
// ---------------------------------------------------------------------------
__global__ __launch_bounds__(64) void epi_kernel(
    const float* __restrict__ partZ, const float* __restrict__ W,
    const float* __restrict__ bias, float* __restrict__ out) {
  __shared__ float sW[1024];
  __shared__ float sb[32];
  const int tid = threadIdx.x;
  for (int i = tid; i < 1024; i += 64) sW[i] = W[i];
  if (tid < 32) sb[tid] = bias[tid];
  __syncthreads();

  const int m = blockIdx.x * 64 + tid;
  float zz[32];
#pragma unroll
  for (int i = 0; i < 32; ++i) zz[i] = 0.f;
  const float* p = partZ + (size_t)m * 32;
  for (int s = 0; s < KSPLIT; ++s) {
    const float* ps = p + (size_t)s * N_NODES * 32;
#pragma unroll
    for (int i = 0; i < 8; ++i) {
      f32x4 v = *(const f32x4*)(ps + i * 4);
      zz[4 * i + 0] += v[0]; zz[4 * i + 1] += v[1];
      zz[4 * i + 2] += v[2]; zz[4 * i + 3] += v[3];
    }
  }
#pragma unroll
  for (int o = 0; o < 32; o += 4) {
    f32x4 r;
#pragma unroll
    for (int q = 0; q < 4; ++q) {
      float a = sb[o + q];
#pragma unroll
      for (int d = 0; d < 32; ++d) a = fmaf(zz[d], sW[(o + q) * 32 + d], a);
      r[q] = fmaxf(a, 0.f);
    }
    *(f32x4*)(out + (size_t)m * 32 + o) = r;
  }
}

extern "C" void kernel_launch(void* const* d_in, const int* in_sizes, int n_in,
                              void* d_out, int out_size, void* d_ws, size_t ws_size,
                              hipStream_t stream) {
  const float* A = (const float*)d_in[0];
  const float* X = (const float*)d_in[1];
  const float* W = (const float*)d_in[2];
  const float* b = (const float*)d_in[3];
  const void*  keep_raw = (const void*)d_in[4];
  float* out = (float*)d_out;

  const size_t xm_bytes   = (size_t)NSLICES * SLICE_US * 2;        // 2,621,440
  const size_t partz_bytes = (size_t)KSPLIT * N_NODES * 32 * 4;    // 8,388,608
  if (ws_size < MASK_WS + xm_bytes + partz_bytes) return;  // need ~11 MB

  unsigned char* mk = (unsigned char*)d_ws;
  unsigned short* XmG = (unsigned short*)((char*)d_ws + MASK_WS);
  float* partZ = (float*)((char*)d_ws + MASK_WS + xm_bytes);

  mask_norm_kernel<<<dim3(MASK_N / 256), 256, 0, stream>>>(keep_raw, mk);
  prep_kernel<<<dim3((N_NODES * NCOLS) / 256), 256, 0, stream>>>(X, mk, XmG);
  gemm_kernel<<<dim3(N_NODES / 256, KSPLIT), 512, 0, stream>>>(A, XmG, mk, partZ);
  epi_kernel<<<dim3(N_NODES / 64), 64, 0, stream>>>(partZ, W, b, out);
}